// Round 1
// baseline (9588.704 us; speedup 1.0000x reference)
//
#include <hip/hip_runtime.h>

typedef __attribute__((ext_vector_type(8))) short short8;
typedef __attribute__((ext_vector_type(4))) float f32x4;
typedef unsigned short u16;

#define T_LEN 256
#define NBLK 128
#define CHUNK_USHORT 512      // one 1KB fragment chunk = 512 bf16
#define STEP_USHORT 32768     // 16 ktiles * 4 ntiles * 512 = 64KB per step

// workspace layout (bytes)
#define OFF_X0 0u
#define SZ_X0 (256u*65536u)          // [t][kt<16][nt][lane][8] bf16
#define OFF_Y0 (OFF_X0 + SZ_X0)
#define SZ_Y0 SZ_X0
#define OFF_HB (OFF_Y0 + SZ_Y0)
#define SZ_HB (2u*65536u)            // double-buffered h (c_new), frag layout
#define OFF_POOL (OFF_HB + SZ_HB)
#define SZ_POOL (512u*64u*4u)        // sum_t o-gate, [h][b] fp32
#define OFF_BAR (OFF_POOL + SZ_POOL)
#define SZ_BAR (512u*128u)           // 512 step counters, 128B stride

__device__ __forceinline__ u16 f2bf(float x) {
  unsigned u = __builtin_bit_cast(unsigned, x);
  return (u16)((u + 0x7fffu + ((u >> 16) & 1u)) >> 16);
}
__device__ __forceinline__ float sigf(float x) { return 1.f / (1.f + __expf(-x)); }
__device__ __forceinline__ float tanhfast(float x) {
  float e = __expf(2.f * x);
  return 1.f - 2.f / (e + 1.f);
}

// ---- embedding gather into MFMA-B fragment layout (bf16) ----
// thread -> (chunk c = t*64 + kt*4 + nt, lane). value[j] = emb[in[b,t]][k0+j]
__global__ void gather_x0(const int* __restrict__ in_t, const float* __restrict__ emb,
                          u16* __restrict__ x0) {
  int gid = blockIdx.x * 256 + threadIdx.x;
  int c = gid >> 6, lane = gid & 63;
  int t = c >> 6, rem = c & 63;
  int kt = rem >> 2, nt = rem & 3;
  int b = nt * 16 + (lane & 15);
  int k0 = kt * 32 + ((lane >> 4) * 8);
  int row = in_t[b * T_LEN + t];
  const float4* ep = (const float4*)(emb + (size_t)row * 512 + k0);
  float4 lo = ep[0], hi = ep[1];
  short8 fr;
  fr[0] = (short)f2bf(lo.x); fr[1] = (short)f2bf(lo.y);
  fr[2] = (short)f2bf(lo.z); fr[3] = (short)f2bf(lo.w);
  fr[4] = (short)f2bf(hi.x); fr[5] = (short)f2bf(hi.y);
  fr[6] = (short)f2bf(hi.z); fr[7] = (short)f2bf(hi.w);
  *(short8*)(x0 + (size_t)c * CHUNK_USHORT + lane * 8) = fr;
}

// ---- persistent recurrent kernel ----
// block = (row-group rb: h-indices [8rb,8rb+8), 4 gates = 32 rows) x (sample half sb: 32 samples)
// wave w covers K-slice [256w, 256w+256); weights live in 64 VGPRs per wave.
__global__ __launch_bounds__(256) void lstm_persist(
    const float* __restrict__ wx, const float* __restrict__ bx,
    const float* __restrict__ wh, const float* __restrict__ bh,
    const u16* __restrict__ x0, u16* __restrict__ y0,
    u16* __restrict__ hbuf, float* __restrict__ pool, unsigned* __restrict__ bar) {
  __shared__ float part[4][32][32];   // [wave][local gate row][local sample]
  __shared__ float bias_s[32];
  const int tid = threadIdx.x;
  const int w = tid >> 6, lane = tid & 63;
  const int rb = blockIdx.x >> 1;
  const int sb = blockIdx.x & 1;
  // elementwise ownership: one (h-index, sample) pair per thread
  const int hl = tid >> 5;            // 0..7 local h index
  const int nl = tid & 31;            // 0..31 local sample
  const int n = sb * 32 + nl;         // global sample
  float c_state = 0.f;                // holds prev h_new (the unpack bug)
  float opool = 0.f;

  for (int layer = 0; layer < 2; ++layer) {
    // load weight fragments (fp32 -> bf16) for this wave's K slice
    short8 afrag[2][8];
#pragma unroll
    for (int mt = 0; mt < 2; ++mt) {
      const int ml = mt * 16 + (lane & 15);
      const int g = ml >> 3;
      const int o = rb * 8 + (ml & 7);
      const float* wxrow = wx + (((size_t)(layer * 4 + g) * 512 + o) * 512);
      const float* whrow = wh + (((size_t)(layer * 4 + g) * 512 + o) * 512);
#pragma unroll
      for (int ks = 0; ks < 8; ++ks) {
        const int k = w * 256 + ks * 32 + ((lane >> 4) * 8);
        const float* src = (k < 512) ? (wxrow + k) : (whrow + (k - 512));
        float4 lo = *(const float4*)src;
        float4 hi = *(const float4*)(src + 4);
        short8 fr;
        fr[0] = (short)f2bf(lo.x); fr[1] = (short)f2bf(lo.y);
        fr[2] = (short)f2bf(lo.z); fr[3] = (short)f2bf(lo.w);
        fr[4] = (short)f2bf(hi.x); fr[5] = (short)f2bf(hi.y);
        fr[6] = (short)f2bf(hi.z); fr[7] = (short)f2bf(hi.w);
        afrag[mt][ks] = fr;
      }
    }
    if (tid < 32) {
      const int g = tid >> 3, o = rb * 8 + (tid & 7);
      bias_s[tid] = bx[(layer * 4 + g) * 512 + o] + bh[(layer * 4 + g) * 512 + o];
    }
    __syncthreads();

    const u16* xl = (layer == 0) ? x0 : y0;
    for (int t = 0; t < T_LEN; ++t) {
      const int s = layer * T_LEN + t;
      const u16* xstep = xl + (size_t)t * STEP_USHORT;
      const u16* hstep = hbuf + (size_t)(s & 1) * STEP_USHORT;
      f32x4 acc[2][2] = {};
#pragma unroll
      for (int ks = 0; ks < 8; ++ks) {
        const int kt = w * 8 + ks;
        const u16* base = (kt < 16) ? (xstep + kt * 4 * CHUNK_USHORT)
                                    : (hstep + (kt - 16) * 4 * CHUNK_USHORT);
        short8 bfr[2];
#pragma unroll
        for (int ntl = 0; ntl < 2; ++ntl) {
          const int nt = sb * 2 + ntl;
          bfr[ntl] = *(const short8*)(base + nt * CHUNK_USHORT + lane * 8);
        }
#pragma unroll
        for (int mt = 0; mt < 2; ++mt)
#pragma unroll
          for (int ntl = 0; ntl < 2; ++ntl)
            acc[mt][ntl] = __builtin_amdgcn_mfma_f32_16x16x32_bf16(
                afrag[mt][ks], bfr[ntl], acc[mt][ntl], 0, 0, 0);
      }
      // partial sums to LDS; C/D layout: col = lane&15, row = 4*(lane>>4)+r
#pragma unroll
      for (int mt = 0; mt < 2; ++mt)
#pragma unroll
        for (int ntl = 0; ntl < 2; ++ntl)
#pragma unroll
          for (int r = 0; r < 4; ++r)
            part[w][mt * 16 + (lane >> 4) * 4 + r][ntl * 16 + (lane & 15)] =
                acc[mt][ntl][r];
      __syncthreads();

      // K-reduction + gate nonlinearity + state update (one pair per thread)
      float v[4];
#pragma unroll
      for (int g = 0; g < 4; ++g) {
        const int lr = g * 8 + hl;
        v[g] = part[0][lr][nl] + part[1][lr][nl] + part[2][lr][nl] +
               part[3][lr][nl] + bias_s[lr];
      }
      const float ig = sigf(v[0]);
      const float fg = sigf(v[1]);
      const float gg = tanhfast(v[2]);
      const float og = sigf(v[3]);
      const float cn = fg * c_state + ig * gg;  // c input = prev h_new (bug)
      const float hn = og * tanhfast(cn);
      c_state = hn;
      {
        const int hi = rb * 8 + hl;
        const int kk = hi & 31, ktl = hi >> 5;
        // c_new -> next step's matvec-h input (bug: h <- c_new)
        u16* dst = hbuf + (size_t)((s + 1) & 1) * STEP_USHORT +
                   (ktl * 4 + (n >> 4)) * CHUNK_USHORT +
                   ((kk >> 3) * 16 + (n & 15)) * 8 + (kk & 7);
        *dst = f2bf(cn);
        if (layer == 0) {
          // o-gate is the emitted sequence -> layer 1 input, frag layout
          u16* yd = y0 + (size_t)t * STEP_USHORT +
                    ((hi >> 5) * 4 + (n >> 4)) * CHUNK_USHORT +
                    (((hi & 31) >> 3) * 16 + (n & 15)) * 8 + (hi & 7);
          *yd = f2bf(og);
        } else {
          opool += og;
        }
      }
      // inter-block barrier for step s
      __threadfence();
      __syncthreads();
      if (tid == 0) {
        __hip_atomic_fetch_add(&bar[s * 32], 1u, __ATOMIC_RELEASE,
                               __HIP_MEMORY_SCOPE_AGENT);
        while (__hip_atomic_load(&bar[s * 32], __ATOMIC_ACQUIRE,
                                 __HIP_MEMORY_SCOPE_AGENT) < NBLK)
          __builtin_amdgcn_s_sleep(2);
      }
      __syncthreads();
    }
  }
  pool[(size_t)(rb * 8 + hl) * 64 + n] = opool;
}

// ---- final pooled @ wo.T + bo -> sigmoid ----
__global__ void finalize_k(const float* __restrict__ pool, const float* __restrict__ wo,
                           const float* __restrict__ bo, float* __restrict__ out) {
  const int b = threadIdx.x;  // 64 threads, lane b; pool[h][0..63] is contiguous
  float s = 0.f;
  for (int h = 0; h < 512; ++h) s += pool[h * 64 + b] * wo[h];
  out[b] = sigf(s * (1.f / 256.f) + bo[0]);
}

extern "C" void kernel_launch(void* const* d_in, const int* in_sizes, int n_in,
                              void* d_out, int out_size, void* d_ws, size_t ws_size,
                              hipStream_t stream) {
  const int* in_t = (const int*)d_in[0];
  const float* emb = (const float*)d_in[1];
  const float* wx = (const float*)d_in[2];
  const float* bx = (const float*)d_in[3];
  const float* wh = (const float*)d_in[4];
  const float* bh = (const float*)d_in[5];
  const float* wo = (const float*)d_in[6];
  const float* bo = (const float*)d_in[7];
  float* out = (float*)d_out;
  char* ws = (char*)d_ws;
  u16* x0 = (u16*)(ws + OFF_X0);
  u16* y0 = (u16*)(ws + OFF_Y0);
  u16* hb = (u16*)(ws + OFF_HB);
  float* pool = (float*)(ws + OFF_POOL);
  unsigned* bar = (unsigned*)(ws + OFF_BAR);

  hipMemsetAsync(ws + OFF_HB, 0, SZ_HB, stream);    // h=0 at t=0
  hipMemsetAsync(ws + OFF_BAR, 0, SZ_BAR, stream);  // barrier counters
  gather_x0<<<4096, 256, 0, stream>>>(in_t, emb, x0);
  lstm_persist<<<NBLK, 256, 0, stream>>>(wx, bx, wh, bh, x0, y0, hb, pool, bar);
  finalize_k<<<1, 64, 0, stream>>>(pool, wo, bo, out);
}

// Round 2
// 3083.038 us; speedup vs baseline: 3.1101x; 3.1101x over previous
//
#include <hip/hip_runtime.h>

typedef __attribute__((ext_vector_type(8))) short short8;
typedef __attribute__((ext_vector_type(4))) float f32x4;
typedef unsigned short u16;

#define T_LEN 256
#define STEP_U16 32768          // 16 ktiles * 4 ntiles * 512 u16 = 64KB per step
#define CHUNK_U16 512

// workspace layout (bytes)
#define OFF_X0 0u
#define SZ_X0 (256u * 65536u)   // [t][kt<16][nt][lane][8] bf16 = 16MB
#define OFF_Y0 (OFF_X0 + SZ_X0)
#define SZ_Y0 SZ_X0
#define OFF_HB (OFF_Y0 + SZ_Y0)
#define SZ_HB (2u * 2u * 65536u)   // [layer][slot] h-fragments (c_new), 256KB
#define OFF_POOL (OFF_HB + SZ_HB)
#define SZ_POOL (512u * 64u * 4u)
#define OFF_HFLAG (OFF_POOL + SZ_POOL)
#define SZ_HFLAG (4u * 32u * 128u)   // [group(layer,sb)][rb], 128B stride
#define OFF_YFLAG (OFF_HFLAG + SZ_HFLAG)
#define SZ_YFLAG (2u * 32u * 128u)   // [sb][rb]

__device__ __forceinline__ u16 f2bf(float x) {
  unsigned u = __builtin_bit_cast(unsigned, x);
  return (u16)((u + 0x7fffu + ((u >> 16) & 1u)) >> 16);
}
__device__ __forceinline__ float sigf(float x) { return 1.f / (1.f + __expf(-x)); }
__device__ __forceinline__ float tanhfast(float x) {
  float e = __expf(2.f * x);
  return 1.f - 2.f / (e + 1.f);
}

// ---- embedding gather into MFMA-B fragment layout (bf16) ----
__global__ void gather_x0(const int* __restrict__ in_t, const float* __restrict__ emb,
                          u16* __restrict__ x0) {
  int gid = blockIdx.x * 256 + threadIdx.x;
  int c = gid >> 6, lane = gid & 63;
  int t = c >> 6, rem = c & 63;
  int kt = rem >> 2, nt = rem & 3;
  int b = nt * 16 + (lane & 15);
  int k0 = kt * 32 + ((lane >> 4) * 8);
  int row = in_t[b * T_LEN + t];
  const float4* ep = (const float4*)(emb + (size_t)row * 512 + k0);
  float4 lo = ep[0], hi = ep[1];
  short8 fr;
  fr[0] = (short)f2bf(lo.x); fr[1] = (short)f2bf(lo.y);
  fr[2] = (short)f2bf(lo.z); fr[3] = (short)f2bf(lo.w);
  fr[4] = (short)f2bf(hi.x); fr[5] = (short)f2bf(hi.y);
  fr[6] = (short)f2bf(hi.z); fr[7] = (short)f2bf(hi.w);
  *(short8*)(x0 + (size_t)c * CHUNK_U16 + lane * 8) = fr;
}

// ---- persistent recurrent kernel, layer-pipelined ----
// 128 blocks. bid decode: low3=bid&7; group g=low3>>1 (layer=g>>1, sb=g&1);
// rb = (bid>>3)*2 + (low3&1)  in [0,32). Block owns h-indices [16rb,16rb+16),
// samples [32sb, 32sb+32). Wave w: K-slice [256w,256w+256) (w<2: x-side, w>=2: h-side).
__global__ __launch_bounds__(256, 1) void lstm_persist(
    const float* __restrict__ wx, const float* __restrict__ bx,
    const float* __restrict__ wh, const float* __restrict__ bh,
    const u16* __restrict__ x0, u16* __restrict__ y0,
    u16* __restrict__ hbuf, float* __restrict__ pool,
    unsigned* __restrict__ hflag, unsigned* __restrict__ yflag) {
  __shared__ float part[4][64][32];
  __shared__ float bias_s[64];
  __shared__ u16 c_lds[32][16];
  __shared__ u16 o_lds[32][16];

  const int tid = threadIdx.x;
  const int w = tid >> 6, lane = tid & 63;
  const int bid = blockIdx.x;
  const int low3 = bid & 7;
  const int g4 = low3 >> 1;
  const int layer = g4 >> 1;
  const int sb = g4 & 1;
  const int rb = ((bid >> 3) << 1) | (low3 & 1);

  // ---- load weight fragments (fp32 -> bf16), gate mt = m-tile ----
  short8 afrag[4][8];
  {
    const int hl = lane & 15;
    const int kbase = w * 256 + ((lane >> 4) * 8);
#pragma unroll
    for (int gt = 0; gt < 4; ++gt) {
      const size_t row = ((size_t)(layer * 4 + gt) * 512 + rb * 16 + hl) * 512;
      const float* wxrow = wx + row;
      const float* whrow = wh + row;
#pragma unroll
      for (int ks = 0; ks < 8; ++ks) {
        const int k = kbase + ks * 32;
        const float* src = (k < 512) ? (wxrow + k) : (whrow + (k - 512));
        float4 lo = *(const float4*)src;
        float4 hi = *(const float4*)(src + 4);
        short8 fr;
        fr[0] = (short)f2bf(lo.x); fr[1] = (short)f2bf(lo.y);
        fr[2] = (short)f2bf(lo.z); fr[3] = (short)f2bf(lo.w);
        fr[4] = (short)f2bf(hi.x); fr[5] = (short)f2bf(hi.y);
        fr[6] = (short)f2bf(hi.z); fr[7] = (short)f2bf(hi.w);
        afrag[gt][ks] = fr;
      }
    }
  }
  if (tid < 64) {
    const int gt = tid >> 4, ho = rb * 16 + (tid & 15);
    bias_s[tid] = bx[(layer * 4 + gt) * 512 + ho] + bh[(layer * 4 + gt) * 512 + ho];
  }
  __syncthreads();

  const u16* xl = (layer == 0) ? x0 : y0;
  u16* hb = hbuf + (size_t)layer * 2 * STEP_U16;
  unsigned* my_hflag = hflag + ((size_t)g4 * 32 + rb) * 32;
  unsigned* grp_hflag = hflag + (size_t)g4 * 32 * 32;
  unsigned* grp_yflag = yflag + (size_t)sb * 32 * 32;
  unsigned* my_yflag = yflag + ((size_t)sb * 32 + rb) * 32;

  float2 cst = {0.f, 0.f};
  float2 opool = {0.f, 0.f};
  const int hl0 = tid >> 5;   // 0..7
  const int nl = tid & 31;

  for (int t = 0; t < T_LEN; ++t) {
    // ---- wait for this wave's inputs (w<2: x-side, w>=2: h-side) ----
    {
      const bool needpoll = (layer == 1) || (w >= 2);
      if (needpoll) {
        unsigned* fbase = (w < 2) ? grp_yflag : grp_hflag;
        const unsigned tgt = (w < 2) ? (unsigned)(t + 1) : (unsigned)t;
        unsigned* pf = fbase + (lane & 31) * 32;
        for (;;) {
          unsigned v = __hip_atomic_load(pf, __ATOMIC_ACQUIRE, __HIP_MEMORY_SCOPE_AGENT);
          if (__all((int)(v >= tgt))) break;
          __builtin_amdgcn_s_sleep(1);
        }
      }
    }

    const u16* xstep = xl + (size_t)t * STEP_U16;
    const u16* hstep = hb + (size_t)(t & 1) * STEP_U16;
    f32x4 acc[4][2] = {};
#pragma unroll
    for (int ks = 0; ks < 8; ++ks) {
      const int kt = w * 8 + ks;
      const u16* base = (kt < 16) ? (xstep + kt * 4 * CHUNK_U16)
                                  : (hstep + (kt - 16) * 4 * CHUNK_U16);
      short8 bfr[2];
#pragma unroll
      for (int ntl = 0; ntl < 2; ++ntl)
        bfr[ntl] = *(const short8*)(base + (sb * 2 + ntl) * CHUNK_U16 + lane * 8);
#pragma unroll
      for (int gt = 0; gt < 4; ++gt)
#pragma unroll
        for (int ntl = 0; ntl < 2; ++ntl)
          acc[gt][ntl] = __builtin_amdgcn_mfma_f32_16x16x32_bf16(
              afrag[gt][ks], bfr[ntl], acc[gt][ntl], 0, 0, 0);
    }

    __syncthreads();  // sync_A: prev iter's part readers done
#pragma unroll
    for (int gt = 0; gt < 4; ++gt)
#pragma unroll
      for (int ntl = 0; ntl < 2; ++ntl)
#pragma unroll
        for (int r = 0; r < 4; ++r)
          part[w][gt * 16 + (lane >> 4) * 4 + r][ntl * 16 + (lane & 15)] =
              acc[gt][ntl][r];
    __syncthreads();  // sync_B

    // ---- K-reduce + gates + state update; 2 h-indices per thread ----
#pragma unroll
    for (int half = 0; half < 2; ++half) {
      const int hl = hl0 + half * 8;
      float v[4];
#pragma unroll
      for (int gt = 0; gt < 4; ++gt) {
        const int lr = gt * 16 + hl;
        v[gt] = part[0][lr][nl] + part[1][lr][nl] + part[2][lr][nl] +
                part[3][lr][nl] + bias_s[lr];
      }
      const float ig = sigf(v[0]);
      const float fg = sigf(v[1]);
      const float gg = tanhfast(v[2]);
      const float og = sigf(v[3]);
      const float cprev = half ? cst.y : cst.x;
      const float cn = fg * cprev + ig * gg;   // c input = prev h_new (unpack bug)
      const float hn = og * tanhfast(cn);
      if (half) cst.y = hn; else cst.x = hn;
      c_lds[nl][hl] = f2bf(cn);                // c_new -> next matvec-h input (bug)
      if (layer == 0) {
        o_lds[nl][hl] = f2bf(og);              // o-gate -> layer1 input sequence
      } else {
        if (half) opool.y += og; else opool.x += og;
      }
    }
    __syncthreads();  // sync_C: c_lds/o_lds ready

    // ---- wave 0: coalesced 16B stores + release flags ----
    if (w == 0) {
      const int nls = lane >> 1, hh = lane & 1;
      const int nt = sb * 2 + (nls >> 4);
      const size_t coff = ((size_t)((rb >> 1) * 4 + nt)) * CHUNK_U16 +
                          (((rb & 1) * 2 + hh) * 16 + (nls & 15)) * 8;
      short8 cv = *(const short8*)&c_lds[nls][hh * 8];
      *(short8*)(hb + (size_t)((t + 1) & 1) * STEP_U16 + coff) = cv;
      if (layer == 0) {
        short8 ov = *(const short8*)&o_lds[nls][hh * 8];
        *(short8*)(y0 + (size_t)t * STEP_U16 + coff) = ov;
      }
      if (lane == 0) {
        __hip_atomic_store(my_hflag, (unsigned)(t + 1), __ATOMIC_RELEASE,
                           __HIP_MEMORY_SCOPE_AGENT);
        if (layer == 0)
          __hip_atomic_store(my_yflag, (unsigned)(t + 1), __ATOMIC_RELEASE,
                             __HIP_MEMORY_SCOPE_AGENT);
      }
    }
  }

  if (layer == 1) {
    pool[(size_t)(rb * 16 + hl0) * 64 + sb * 32 + nl] = opool.x;
    pool[(size_t)(rb * 16 + hl0 + 8) * 64 + sb * 32 + nl] = opool.y;
  }
}

// ---- final pooled @ wo.T + bo -> sigmoid ----
__global__ void finalize_k(const float* __restrict__ pool, const float* __restrict__ wo,
                           const float* __restrict__ bo, float* __restrict__ out) {
  const int b = threadIdx.x;
  float s = 0.f;
  for (int h = 0; h < 512; ++h) s += pool[h * 64 + b] * wo[h];
  out[b] = sigf(s * (1.f / 256.f) + bo[0]);
}

extern "C" void kernel_launch(void* const* d_in, const int* in_sizes, int n_in,
                              void* d_out, int out_size, void* d_ws, size_t ws_size,
                              hipStream_t stream) {
  const int* in_t = (const int*)d_in[0];
  const float* emb = (const float*)d_in[1];
  const float* wx = (const float*)d_in[2];
  const float* bx = (const float*)d_in[3];
  const float* wh = (const float*)d_in[4];
  const float* bh = (const float*)d_in[5];
  const float* wo = (const float*)d_in[6];
  const float* bo = (const float*)d_in[7];
  float* out = (float*)d_out;
  char* ws = (char*)d_ws;
  u16* x0 = (u16*)(ws + OFF_X0);
  u16* y0 = (u16*)(ws + OFF_Y0);
  u16* hb = (u16*)(ws + OFF_HB);
  float* pool = (float*)(ws + OFF_POOL);
  unsigned* hflag = (unsigned*)(ws + OFF_HFLAG);
  unsigned* yflag = (unsigned*)(ws + OFF_YFLAG);

  hipMemsetAsync(ws + OFF_HB, 0, SZ_HB, stream);                    // h=0 at t=0
  hipMemsetAsync(ws + OFF_HFLAG, 0, SZ_HFLAG + SZ_YFLAG, stream);   // flags
  gather_x0<<<4096, 256, 0, stream>>>(in_t, emb, x0);
  lstm_persist<<<128, 256, 0, stream>>>(wx, bx, wh, bh, x0, y0, hb, pool,
                                        hflag, yflag);
  finalize_k<<<1, 64, 0, stream>>>(pool, wo, bo, out);
}

// Round 3
// 1854.294 us; speedup vs baseline: 5.1711x; 1.6626x over previous
//
#include <hip/hip_runtime.h>

typedef __attribute__((ext_vector_type(8))) short short8;
typedef __attribute__((ext_vector_type(4))) float f32x4;
typedef __attribute__((ext_vector_type(2))) unsigned long long u64x2;
typedef unsigned short u16;

#define T_LEN 256
#define STEP_U16 32768          // 16 ktiles * 4 ntiles * 512 u16 = 64KB per step
#define CHUNK_U16 512

// workspace layout (bytes)
#define OFF_X0 0u
#define SZ_X0 (256u * 65536u)   // [t][kt<16][nt][lane][8] bf16 = 16MB
#define OFF_Y0 (OFF_X0 + SZ_X0)
#define SZ_Y0 SZ_X0
#define OFF_HB (OFF_Y0 + SZ_Y0)
#define SZ_HB (2u * 2u * 65536u)   // [layer][slot] h-fragments (c_new), 256KB
#define OFF_POOL (OFF_HB + SZ_HB)
#define SZ_POOL (512u * 64u * 4u)
#define OFF_HFLAG (OFF_POOL + SZ_POOL)
#define SZ_HFLAG (4u * 32u * 128u)   // [group(layer,sb)][rb], 128B stride
#define OFF_YFLAG (OFF_HFLAG + SZ_HFLAG)
#define SZ_YFLAG (2u * 32u * 128u)   // [sb][rb]

__device__ __forceinline__ u16 f2bf(float x) {
  unsigned u = __builtin_bit_cast(unsigned, x);
  return (u16)((u + 0x7fffu + ((u >> 16) & 1u)) >> 16);
}
__device__ __forceinline__ float sigf(float x) { return 1.f / (1.f + __expf(-x)); }
__device__ __forceinline__ float tanhfast(float x) {
  float e = __expf(2.f * x);
  return 1.f - 2.f / (e + 1.f);
}

// LLC-coherent (sc1) 16B load/store as 2x relaxed agent-scope 64-bit atomics.
// No acquire/release -> no buffer_inv / buffer_wbl2 cache maintenance.
__device__ __forceinline__ short8 ld16_llc(const u16* p) {
  const unsigned long long* q = (const unsigned long long*)p;
  u64x2 u;
  u[0] = __hip_atomic_load(q + 0, __ATOMIC_RELAXED, __HIP_MEMORY_SCOPE_AGENT);
  u[1] = __hip_atomic_load(q + 1, __ATOMIC_RELAXED, __HIP_MEMORY_SCOPE_AGENT);
  return __builtin_bit_cast(short8, u);
}
__device__ __forceinline__ void st16_llc(u16* p, short8 v) {
  u64x2 u = __builtin_bit_cast(u64x2, v);
  unsigned long long* q = (unsigned long long*)p;
  __hip_atomic_store(q + 0, u[0], __ATOMIC_RELAXED, __HIP_MEMORY_SCOPE_AGENT);
  __hip_atomic_store(q + 1, u[1], __ATOMIC_RELAXED, __HIP_MEMORY_SCOPE_AGENT);
}

// ---- embedding gather into MFMA-B fragment layout (bf16) ----
__global__ void gather_x0(const int* __restrict__ in_t, const float* __restrict__ emb,
                          u16* __restrict__ x0) {
  int gid = blockIdx.x * 256 + threadIdx.x;
  int c = gid >> 6, lane = gid & 63;
  int t = c >> 6, rem = c & 63;
  int kt = rem >> 2, nt = rem & 3;
  int b = nt * 16 + (lane & 15);
  int k0 = kt * 32 + ((lane >> 4) * 8);
  int row = in_t[b * T_LEN + t];
  const float4* ep = (const float4*)(emb + (size_t)row * 512 + k0);
  float4 lo = ep[0], hi = ep[1];
  short8 fr;
  fr[0] = (short)f2bf(lo.x); fr[1] = (short)f2bf(lo.y);
  fr[2] = (short)f2bf(lo.z); fr[3] = (short)f2bf(lo.w);
  fr[4] = (short)f2bf(hi.x); fr[5] = (short)f2bf(hi.y);
  fr[6] = (short)f2bf(hi.z); fr[7] = (short)f2bf(hi.w);
  *(short8*)(x0 + (size_t)c * CHUNK_U16 + lane * 8) = fr;
}

// ---- persistent recurrent kernel, layer-pipelined ----
// 128 blocks. low3=bid&7; group g4=low3>>1 (layer=g4>>1, sb=g4&1);
// rb = (bid>>3)*2 + (low3&1) in [0,32). Block: h-indices [16rb,16rb+16),
// samples [32sb,32sb+32). Wave w: K-slice [256w,256w+256) (w<2 x-side, w>=2 h-side).
__global__ __launch_bounds__(256, 1) void lstm_persist(
    const float* __restrict__ wx, const float* __restrict__ bx,
    const float* __restrict__ wh, const float* __restrict__ bh,
    const u16* __restrict__ x0, u16* __restrict__ y0,
    u16* __restrict__ hbuf, float* __restrict__ pool,
    unsigned* __restrict__ hflag, unsigned* __restrict__ yflag) {
  __shared__ float part[4][64][32];
  __shared__ float bias_s[64];
  __shared__ u16 c_lds[32][16];
  __shared__ u16 o_lds[32][16];

  const int tid = threadIdx.x;
  const int w = tid >> 6, lane = tid & 63;
  const int bid = blockIdx.x;
  const int low3 = bid & 7;
  const int g4 = low3 >> 1;
  const int layer = g4 >> 1;
  const int sb = g4 & 1;
  const int rb = ((bid >> 3) << 1) | (low3 & 1);

  // ---- load weight fragments (fp32 -> bf16) ----
  short8 afrag[4][8];
  {
    const int hl = lane & 15;
    const int kbase = w * 256 + ((lane >> 4) * 8);
#pragma unroll
    for (int gt = 0; gt < 4; ++gt) {
      const size_t row = ((size_t)(layer * 4 + gt) * 512 + rb * 16 + hl) * 512;
      const float* wxrow = wx + row;
      const float* whrow = wh + row;
#pragma unroll
      for (int ks = 0; ks < 8; ++ks) {
        const int k = kbase + ks * 32;
        const float* src = (k < 512) ? (wxrow + k) : (whrow + (k - 512));
        float4 lo = *(const float4*)src;
        float4 hi = *(const float4*)(src + 4);
        short8 fr;
        fr[0] = (short)f2bf(lo.x); fr[1] = (short)f2bf(lo.y);
        fr[2] = (short)f2bf(lo.z); fr[3] = (short)f2bf(lo.w);
        fr[4] = (short)f2bf(hi.x); fr[5] = (short)f2bf(hi.y);
        fr[6] = (short)f2bf(hi.z); fr[7] = (short)f2bf(hi.w);
        afrag[gt][ks] = fr;
      }
    }
  }
  if (tid < 64) {
    const int gt = tid >> 4, ho = rb * 16 + (tid & 15);
    bias_s[tid] = bx[(layer * 4 + gt) * 512 + ho] + bh[(layer * 4 + gt) * 512 + ho];
  }
  __syncthreads();

  const u16* xl = (layer == 0) ? x0 : y0;
  u16* hb = hbuf + (size_t)layer * 2 * STEP_U16;
  unsigned* my_hflag = hflag + ((size_t)g4 * 32 + rb) * 32;
  unsigned* grp_hflag = hflag + (size_t)g4 * 32 * 32;
  unsigned* grp_yflag = yflag + (size_t)sb * 32 * 32;
  unsigned* my_yflag = yflag + ((size_t)sb * 32 + rb) * 32;

  float2 cst = {0.f, 0.f};
  float2 opool = {0.f, 0.f};
  const int hl0 = tid >> 5;   // 0..7
  const int nl = tid & 31;

  for (int t = 0; t < T_LEN; ++t) {
    // ---- wait for this wave's inputs (relaxed poll, no cache maintenance) ----
    // wave w covers kt [8w,8w+8) -> producer rb range [8w&15 .. +16) of the
    // source vector; only 16 of the 32 group flags matter per wave.
    {
      const bool needpoll = (layer == 1) || (w >= 2);
      if (needpoll) {
        unsigned* fbase = (w < 2) ? grp_yflag : grp_hflag;
        const unsigned tgt = (w < 2) ? (unsigned)(t + 1) : (unsigned)t;
        const int rb0 = (w & 1) * 16;  // wave 0/2 -> rb 0..15, wave 1/3 -> rb 16..31
        unsigned* pf = fbase + (rb0 + (lane & 15)) * 32;
        for (;;) {
          unsigned v = __hip_atomic_load(pf, __ATOMIC_RELAXED, __HIP_MEMORY_SCOPE_AGENT);
          if (__all((int)(v >= tgt))) break;
          __builtin_amdgcn_s_sleep(1);
        }
      }
    }

    const u16* xstep = xl + (size_t)t * STEP_U16;
    const u16* hstep = hb + (size_t)(t & 1) * STEP_U16;
    const bool x_atomic = (layer == 1);
    f32x4 acc[4][2] = {};
#pragma unroll
    for (int ks = 0; ks < 8; ++ks) {
      const int kt = w * 8 + ks;
      short8 bfr[2];
#pragma unroll
      for (int ntl = 0; ntl < 2; ++ntl) {
        const int nt = sb * 2 + ntl;
        if (kt < 16) {
          const u16* p = xstep + kt * 4 * CHUNK_U16 + nt * CHUNK_U16 + lane * 8;
          bfr[ntl] = x_atomic ? ld16_llc(p) : *(const short8*)p;
        } else {
          const u16* p = hstep + (kt - 16) * 4 * CHUNK_U16 + nt * CHUNK_U16 + lane * 8;
          bfr[ntl] = ld16_llc(p);
        }
      }
#pragma unroll
      for (int gt = 0; gt < 4; ++gt)
#pragma unroll
        for (int ntl = 0; ntl < 2; ++ntl)
          acc[gt][ntl] = __builtin_amdgcn_mfma_f32_16x16x32_bf16(
              afrag[gt][ks], bfr[ntl], acc[gt][ntl], 0, 0, 0);
    }

    __syncthreads();  // sync_A: prev iter's part readers done
#pragma unroll
    for (int gt = 0; gt < 4; ++gt)
#pragma unroll
      for (int ntl = 0; ntl < 2; ++ntl)
#pragma unroll
        for (int r = 0; r < 4; ++r)
          part[w][gt * 16 + (lane >> 4) * 4 + r][ntl * 16 + (lane & 15)] =
              acc[gt][ntl][r];
    __syncthreads();  // sync_B

    // ---- K-reduce + gates + state update; 2 h-indices per thread ----
#pragma unroll
    for (int half = 0; half < 2; ++half) {
      const int hl = hl0 + half * 8;
      float v[4];
#pragma unroll
      for (int gt = 0; gt < 4; ++gt) {
        const int lr = gt * 16 + hl;
        v[gt] = part[0][lr][nl] + part[1][lr][nl] + part[2][lr][nl] +
                part[3][lr][nl] + bias_s[lr];
      }
      const float ig = sigf(v[0]);
      const float fg = sigf(v[1]);
      const float gg = tanhfast(v[2]);
      const float og = sigf(v[3]);
      const float cprev = half ? cst.y : cst.x;
      const float cn = fg * cprev + ig * gg;   // c input = prev h_new (unpack bug)
      const float hn = og * tanhfast(cn);
      if (half) cst.y = hn; else cst.x = hn;
      c_lds[nl][hl] = f2bf(cn);                // c_new -> next matvec-h input (bug)
      if (layer == 0) {
        o_lds[nl][hl] = f2bf(og);              // o-gate -> layer1 input sequence
      } else {
        if (half) opool.y += og; else opool.x += og;
      }
    }
    __syncthreads();  // sync_C: c_lds/o_lds ready

    // ---- wave 0: coalesced 16B LLC stores + flag release (waitcnt-ordered) ----
    if (w == 0) {
      const int nls = lane >> 1, hh = lane & 1;
      const int nt = sb * 2 + (nls >> 4);
      const size_t coff = ((size_t)((rb >> 1) * 4 + nt)) * CHUNK_U16 +
                          (((rb & 1) * 2 + hh) * 16 + (nls & 15)) * 8;
      short8 cv = *(const short8*)&c_lds[nls][hh * 8];
      st16_llc(hb + (size_t)((t + 1) & 1) * STEP_U16 + coff, cv);
      if (layer == 0) {
        short8 ov = *(const short8*)&o_lds[nls][hh * 8];
        st16_llc(y0 + (size_t)t * STEP_U16 + coff, ov);
      }
      // ensure data stores completed to LLC before flags become visible
      asm volatile("s_waitcnt vmcnt(0)" ::: "memory");
      if (lane == 0) {
        __hip_atomic_store(my_hflag, (unsigned)(t + 1), __ATOMIC_RELAXED,
                           __HIP_MEMORY_SCOPE_AGENT);
        if (layer == 0)
          __hip_atomic_store(my_yflag, (unsigned)(t + 1), __ATOMIC_RELAXED,
                             __HIP_MEMORY_SCOPE_AGENT);
      }
    }
  }

  if (layer == 1) {
    pool[(size_t)(rb * 16 + hl0) * 64 + sb * 32 + nl] = opool.x;
    pool[(size_t)(rb * 16 + hl0 + 8) * 64 + sb * 32 + nl] = opool.y;
  }
}

// ---- final pooled @ wo.T + bo -> sigmoid ----
__global__ void finalize_k(const float* __restrict__ pool, const float* __restrict__ wo,
                           const float* __restrict__ bo, float* __restrict__ out) {
  const int b = threadIdx.x;
  float s = 0.f;
  for (int h = 0; h < 512; ++h) s += pool[h * 64 + b] * wo[h];
  out[b] = sigf(s * (1.f / 256.f) + bo[0]);
}

extern "C" void kernel_launch(void* const* d_in, const int* in_sizes, int n_in,
                              void* d_out, int out_size, void* d_ws, size_t ws_size,
                              hipStream_t stream) {
  const int* in_t = (const int*)d_in[0];
  const float* emb = (const float*)d_in[1];
  const float* wx = (const float*)d_in[2];
  const float* bx = (const float*)d_in[3];
  const float* wh = (const float*)d_in[4];
  const float* bh = (const float*)d_in[5];
  const float* wo = (const float*)d_in[6];
  const float* bo = (const float*)d_in[7];
  float* out = (float*)d_out;
  char* ws = (char*)d_ws;
  u16* x0 = (u16*)(ws + OFF_X0);
  u16* y0 = (u16*)(ws + OFF_Y0);
  u16* hb = (u16*)(ws + OFF_HB);
  float* pool = (float*)(ws + OFF_POOL);
  unsigned* hflag = (unsigned*)(ws + OFF_HFLAG);
  unsigned* yflag = (unsigned*)(ws + OFF_YFLAG);

  hipMemsetAsync(ws + OFF_HB, 0, SZ_HB, stream);                    // h=0 at t=0
  hipMemsetAsync(ws + OFF_HFLAG, 0, SZ_HFLAG + SZ_YFLAG, stream);   // flags
  gather_x0<<<4096, 256, 0, stream>>>(in_t, emb, x0);
  lstm_persist<<<128, 256, 0, stream>>>(wx, bx, wh, bh, x0, y0, hb, pool,
                                        hflag, yflag);
  finalize_k<<<1, 64, 0, stream>>>(pool, wo, bo, out);
}